// Round 8
// baseline (395.173 us; speedup 1.0000x reference)
//
#include <hip/hip_runtime.h>
#include <hip/hip_bf16.h>

// Swin-V2 window attention, fused. B=2048 windows, N=64 tokens, C=256, H=8, Dh=32.
// R8 = deferred-V win_attn (R6 structure) with the otk->ob store reverted to f2bf
// (the cvt2-on-MFMA-accumulator pack is the R3..R7 bug: R6 and R7 — different
// kernels, one shared component — failed with bit-identical 1.190186e-01),
// plus the parallel split cpb (table + expand). cvt2 appears ONLY in the
// x-staging path where it was proven in the passing Round-2 bench.
//   cpb_table_kernel:  CPB MLP -> bias table bt[127][8] (127 blocks, wave-parallel).
//   cpb_expand_kernel: bt -> 16*sigmoid in MFMA C-frag layout (formula verbatim); scale[h].
//   convert_kernel:    qkv_weight/proj_w -> bf16; concat qkv bias. (proven verbatim)
//   win_attn_kernel:   1 block/window, 4 waves, wave owns heads {w, w+4}.
//     pass1: Q,K GEMM (x frags from global f32 + cvt2, L1/L2 reuse), cosine-norm
//     epilogues -> per-wave LDS, QK^T + bias + softmax -> P (stride 64, overlays
//     dead q/k), pass2: V GEMM (x re-read, L1-hit) -> v^T LDS, PV -> regs (otk);
//     barrier, otk -> ob via f2bf (overlays wbuf), barrier, proj GEMM.
//   Per-wave LDS 6400 shorts -> block 51,200 B -> 3 blocks/CU LDS-wise.
// mfma_f32_16x16x32_bf16; C/D: col=lane&15, row=(lane>>4)*4+reg;
// A/B frag: M[lane&15][(lane>>4)*8 + j] (contiguous 8 bf16 = 16B ds_read_b128).

typedef __attribute__((ext_vector_type(8))) short bf16x8;
typedef __attribute__((ext_vector_type(4))) short short4v;
typedef __attribute__((ext_vector_type(4))) float f32x4;

__device__ __forceinline__ unsigned short f2bf(float f) {
  union { float f; unsigned int u; } a; a.f = f;
  return (unsigned short)((a.u + 0x7FFFu + ((a.u >> 16) & 1u)) >> 16);  // RNE
}

// packed f32x2 -> bf16x2, single VALU instr; elem0 in low half.
// ONLY safe on plain-VGPR values (global-load results); do NOT feed MFMA
// accumulators directly (AGPR-resident operand miscompiles — R3..R7 bug).
__device__ __forceinline__ unsigned int cvt2(float lo, float hi) {
  unsigned int r;
  asm("v_cvt_pk_bf16_f32 %0, %1, %2" : "=v"(r) : "v"(lo), "v"(hi));
  return r;
}

// ---------------- CPB MLP table: bt[row][h] (parallel) ----------------
__global__ void cpb_table_kernel(const float* __restrict__ w1, const float* __restrict__ b1,
                                 const float* __restrict__ w2, float* __restrict__ bt)
{
  const int row = blockIdx.x;       // 0..126
  const int lane = threadIdx.x;     // 0..63
  float xr = ((float)row - 63.0f) * (8.0f / 63.0f);
  float sgn = (xr > 0.0f) ? 1.0f : ((xr < 0.0f) ? -1.0f : 0.0f);
  float val = sgn * log2f(fabsf(xr) + 1.0f) * (1.0f / 3.0f);  // /log2(8)
  float acc[8];
  #pragma unroll
  for (int hh = 0; hh < 8; ++hh) acc[hh] = 0.0f;
  #pragma unroll
  for (int jj = 0; jj < 8; ++jj) {
    int j = jj * 64 + lane;
    float hv = fmaxf(val * w1[j] + b1[j], 0.0f);
    #pragma unroll
    for (int hh = 0; hh < 8; ++hh) acc[hh] += hv * w2[hh * 512 + j];
  }
  #pragma unroll
  for (int hh = 0; hh < 8; ++hh) {
    #pragma unroll
    for (int m = 1; m < 64; m <<= 1) acc[hh] += __shfl_xor(acc[hh], m);
  }
  if (lane == 0) {
    #pragma unroll
    for (int hh = 0; hh < 8; ++hh) bt[row * 8 + hh] = acc[hh];
  }
}

// ---- expand: rpb[h][mt][nt][lane][r] = 16*sigmoid(bt[row-col+63][h]); scale[h] ----
__global__ void cpb_expand_kernel(const float* __restrict__ bt, const float* __restrict__ ls,
                                  float* __restrict__ rpb, float* __restrict__ scale)
{
  const int i = blockIdx.x * 256 + threadIdx.x;   // 0..32767
  int r = i & 3, lane = (i >> 2) & 63, nt = (i >> 8) & 3, mt = (i >> 10) & 3, hh = i >> 12;
  int row = mt * 16 + (lane >> 4) * 4 + r;
  int col = nt * 16 + (lane & 15);
  float b = bt[(row - col + 63) * 8 + hh];
  rpb[i] = 16.0f / (1.0f + __expf(-b));
  if (i < 8) scale[i] = __expf(fminf(ls[i], 4.605170185988091f));  // ln(100)
}

// ---------------- weight conversion (proven verbatim) ----------------
__global__ void convert_kernel(const float* __restrict__ qw, const float* __restrict__ pw,
                               const float* __restrict__ qb, const float* __restrict__ vb,
                               short* __restrict__ wqkv, short* __restrict__ wproj,
                               float* __restrict__ qkvb)
{
  const int idx = blockIdx.x * 256 + threadIdx.x;
  if (idx < 196608) wqkv[idx] = (short)f2bf(qw[idx]);
  else if (idx - 196608 < 65536) wproj[idx - 196608] = (short)f2bf(pw[idx - 196608]);
  if (idx < 768) qkvb[idx] = (idx < 256) ? qb[idx] : ((idx < 512) ? 0.0f : vb[idx - 512]);
}

// ---------------- fused window attention ----------------
__global__ __launch_bounds__(256, 2) void win_attn_kernel(
    const float* __restrict__ x,
    const short* __restrict__ wqkv,
    const short* __restrict__ wproj,
    const float* __restrict__ qkvb,
    const float* __restrict__ scale,
    const float* __restrict__ rpb,
    const float* __restrict__ projb,
    float* __restrict__ out)
{
  // per wave 6400 shorts: q[0:2560) s40, k[2560:5120) s40;
  // after QK^T: P[0:4096) s64, v^T[4096:6400) s72.
  // ob (stride 264, 16,896 shorts) overlays wbuf after barrier.
  __shared__ short wbuf[4][6400];

  const int tid = threadIdx.x;
  const int wid = tid >> 6;
  const int lane = tid & 63;
  const int lq = lane & 15;
  const int lg = lane >> 4;
  const int blk = blockIdx.x;

  short* qb  = wbuf[wid];
  short* kb  = qb + 2560;
  short* pb  = qb;
  short* vtb = qb + 4096;
  short* ob  = &wbuf[0][0];

  const f32x4 fz = {0.0f, 0.0f, 0.0f, 0.0f};
  const float* xbase = x + ((size_t)blk * 64 + lq) * 256 + lg * 8;

  f32x4 otk[2][2][4];   // [hi][dt][mt], hi is compile-time (loop unrolled)

  #pragma unroll
  for (int hi = 0; hi < 2; ++hi) {
    const int h = wid + hi * 4;
    const short* wqb = wqkv + (h * 32 + lq) * 256 + lg * 8;

    // ---- pass 1: sq/sk = W · x^T (q^T,k^T C-layout) ----
    f32x4 sq[2][4], sk[2][4];
    #pragma unroll
    for (int i = 0; i < 2; ++i)
      #pragma unroll
      for (int j = 0; j < 4; ++j) { sq[i][j] = fz; sk[i][j] = fz; }

    #pragma unroll 2
    for (int ks = 0; ks < 8; ++ks) {
      const int k0 = ks * 32;
      bf16x8 xf[4];
      #pragma unroll
      for (int mt = 0; mt < 4; ++mt) {
        const float* xp = xbase + mt * 4096 + k0;
        float4 a = *(const float4*)xp;
        float4 b = *(const float4*)(xp + 4);
        union { unsigned int u[4]; bf16x8 v; } c;
        c.u[0] = cvt2(a.x, a.y); c.u[1] = cvt2(a.z, a.w);
        c.u[2] = cvt2(b.x, b.y); c.u[3] = cvt2(b.z, b.w);
        xf[mt] = c.v;
      }
      bf16x8 wqf[2], wkf[2];
      #pragma unroll
      for (int dt = 0; dt < 2; ++dt) {
        const short* wp = wqb + dt * 4096 + k0;
        wqf[dt] = *(const bf16x8*)wp;
        wkf[dt] = *(const bf16x8*)(wp + 65536);    // +256 rows
      }
      #pragma unroll
      for (int dt = 0; dt < 2; ++dt)
        #pragma unroll
        for (int mt = 0; mt < 4; ++mt) {
          sq[dt][mt] = __builtin_amdgcn_mfma_f32_16x16x32_bf16(wqf[dt], xf[mt], sq[dt][mt], 0, 0, 0);
          sk[dt][mt] = __builtin_amdgcn_mfma_f32_16x16x32_bf16(wkf[dt], xf[mt], sk[dt][mt], 0, 0, 0);
        }
    }

    // ---- q epilogue: +bias, L2-normalize rows, packed store [token][d] ----
    {
      float qbias[2][4];
      #pragma unroll
      for (int dt = 0; dt < 2; ++dt)
        #pragma unroll
        for (int r = 0; r < 4; ++r)
          qbias[dt][r] = qkvb[h * 32 + dt * 16 + lg * 4 + r];
      #pragma unroll
      for (int mt = 0; mt < 4; ++mt) {
        float vv[2][4];
        float ss = 0.0f;
        #pragma unroll
        for (int dt = 0; dt < 2; ++dt)
          #pragma unroll
          for (int r = 0; r < 4; ++r) {
            vv[dt][r] = sq[dt][mt][r] + qbias[dt][r];
            ss += vv[dt][r] * vv[dt][r];
          }
        ss += __shfl_xor(ss, 16);
        ss += __shfl_xor(ss, 32);
        float rn = 1.0f / fmaxf(sqrtf(ss), 1e-12f);
        #pragma unroll
        for (int dt = 0; dt < 2; ++dt) {
          short4v pk;
          #pragma unroll
          for (int r = 0; r < 4; ++r) pk[r] = (short)f2bf(vv[dt][r] * rn);
          *(short4v*)&qb[(mt * 16 + lq) * 40 + dt * 16 + lg * 4] = pk;
        }
      }
    }
    // ---- k epilogue (bias = 0) ----
    {
      #pragma unroll
      for (int mt = 0; mt < 4; ++mt) {
        float ss = 0.0f;
        #pragma unroll
        for (int dt = 0; dt < 2; ++dt)
          #pragma unroll
          for (int r = 0; r < 4; ++r) ss += sk[dt][mt][r] * sk[dt][mt][r];
        ss += __shfl_xor(ss, 16);
        ss += __shfl_xor(ss, 32);
        float rn = 1.0f / fmaxf(sqrtf(ss), 1e-12f);
        #pragma unroll
        for (int dt = 0; dt < 2; ++dt) {
          short4v pk;
          #pragma unroll
          for (int r = 0; r < 4; ++r) pk[r] = (short)f2bf(sk[dt][mt][r] * rn);
          *(short4v*)&kb[(mt * 16 + lq) * 40 + dt * 16 + lg * 4] = pk;
        }
      }
    }

    // ---- QK^T (K=32, single k-step) ----
    f32x4 s[4][4];
    {
      bf16x8 a2[4], b2[4];
      #pragma unroll
      for (int mt = 0; mt < 4; ++mt)
        a2[mt] = *(const bf16x8*)&qb[(mt * 16 + lq) * 40 + lg * 8];
      #pragma unroll
      for (int nt = 0; nt < 4; ++nt)
        b2[nt] = *(const bf16x8*)&kb[(nt * 16 + lq) * 40 + lg * 8];
      #pragma unroll
      for (int mt = 0; mt < 4; ++mt)
        #pragma unroll
        for (int nt = 0; nt < 4; ++nt)
          s[mt][nt] = __builtin_amdgcn_mfma_f32_16x16x32_bf16(a2[mt], b2[nt], fz, 0, 0, 0);
    }

    // ---- softmax (scale, +rpb, rowwise over 64 cols) -> P (stride 64) ----
    const float sch = scale[h];
    #pragma unroll
    for (int mt = 0; mt < 4; ++mt) {
      f32x4 rp[4];
      #pragma unroll
      for (int nt = 0; nt < 4; ++nt)
        rp[nt] = ((const f32x4*)rpb)[((h * 4 + mt) * 4 + nt) * 64 + lane];
      #pragma unroll
      for (int r = 0; r < 4; ++r) {
        float v0 = s[mt][0][r] * sch + rp[0][r];
        float v1 = s[mt][1][r] * sch + rp[1][r];
        float v2 = s[mt][2][r] * sch + rp[2][r];
        float v3 = s[mt][3][r] * sch + rp[3][r];
        float mx = fmaxf(fmaxf(v0, v1), fmaxf(v2, v3));
        mx = fmaxf(mx, __shfl_xor(mx, 1));
        mx = fmaxf(mx, __shfl_xor(mx, 2));
        mx = fmaxf(mx, __shfl_xor(mx, 4));
        mx = fmaxf(mx, __shfl_xor(mx, 8));
        float e0 = __expf(v0 - mx);
        float e1 = __expf(v1 - mx);
        float e2 = __expf(v2 - mx);
        float e3 = __expf(v3 - mx);
        float sm = e0 + e1 + e2 + e3;
        sm += __shfl_xor(sm, 1);
        sm += __shfl_xor(sm, 2);
        sm += __shfl_xor(sm, 4);
        sm += __shfl_xor(sm, 8);
        float inv = 1.0f / sm;
        const int base = (mt * 16 + lg * 4 + r) * 64;
        pb[base + lq]      = (short)f2bf(e0 * inv);
        pb[base + 16 + lq] = (short)f2bf(e1 * inv);
        pb[base + 32 + lq] = (short)f2bf(e2 * inv);
        pb[base + 48 + lq] = (short)f2bf(e3 * inv);
      }
    }

    // ---- pass 2: sv = x · Wv^T (x re-read, L1/L2-hit) ----
    {
      f32x4 sv[4][2];
      #pragma unroll
      for (int j = 0; j < 4; ++j)
        #pragma unroll
        for (int i = 0; i < 2; ++i) sv[j][i] = fz;

      #pragma unroll 2
      for (int ks = 0; ks < 8; ++ks) {
        const int k0 = ks * 32;
        bf16x8 xf[4];
        #pragma unroll
        for (int mt = 0; mt < 4; ++mt) {
          const float* xp = xbase + mt * 4096 + k0;
          float4 a = *(const float4*)xp;
          float4 b = *(const float4*)(xp + 4);
          union { unsigned int u[4]; bf16x8 v; } c;
          c.u[0] = cvt2(a.x, a.y); c.u[1] = cvt2(a.z, a.w);
          c.u[2] = cvt2(b.x, b.y); c.u[3] = cvt2(b.z, b.w);
          xf[mt] = c.v;
        }
        bf16x8 wvf[2];
        #pragma unroll
        for (int dt = 0; dt < 2; ++dt)
          wvf[dt] = *(const bf16x8*)(wqb + dt * 4096 + k0 + 131072);   // +512 rows
        #pragma unroll
        for (int dt = 0; dt < 2; ++dt)
          #pragma unroll
          for (int mt = 0; mt < 4; ++mt)
            sv[mt][dt] = __builtin_amdgcn_mfma_f32_16x16x32_bf16(xf[mt], wvf[dt], sv[mt][dt], 0, 0, 0);
      }

      // ---- v epilogue: +bias, packed transposed store v^T[d][token] (stride 72) ----
      const float vb0 = qkvb[512 + h * 32 + lq];
      const float vb1 = qkvb[512 + h * 32 + 16 + lq];
      #pragma unroll
      for (int mt = 0; mt < 4; ++mt) {
        short4v p0, p1;
        #pragma unroll
        for (int r = 0; r < 4; ++r) {
          p0[r] = (short)f2bf(sv[mt][0][r] + vb0);
          p1[r] = (short)f2bf(sv[mt][1][r] + vb1);
        }
        *(short4v*)&vtb[lq * 72 + mt * 16 + lg * 4] = p0;
        *(short4v*)&vtb[(16 + lq) * 72 + mt * 16 + lg * 4] = p1;
      }
    }

    // ---- PV: out^T = v^T · P^T -> registers (otk) ----
    #pragma unroll
    for (int dt = 0; dt < 2; ++dt)
      #pragma unroll
      for (int mt = 0; mt < 4; ++mt) otk[hi][dt][mt] = fz;
    #pragma unroll
    for (int kt = 0; kt < 2; ++kt) {
      bf16x8 av2[2], bp[4];
      #pragma unroll
      for (int dt = 0; dt < 2; ++dt)
        av2[dt] = *(const bf16x8*)&vtb[(dt * 16 + lq) * 72 + kt * 32 + lg * 8];
      #pragma unroll
      for (int mt = 0; mt < 4; ++mt)
        bp[mt] = *(const bf16x8*)&pb[(mt * 16 + lq) * 64 + kt * 32 + lg * 8];
      #pragma unroll
      for (int dt = 0; dt < 2; ++dt)
        #pragma unroll
        for (int mt = 0; mt < 4; ++mt)
          otk[hi][dt][mt] = __builtin_amdgcn_mfma_f32_16x16x32_bf16(av2[dt], bp[mt], otk[hi][dt][mt], 0, 0, 0);
    }
  }  // hi

  // ---- all waves done with private buffers: overlay ob on wbuf (f2bf pack) ----
  __syncthreads();
  #pragma unroll
  for (int hi = 0; hi < 2; ++hi) {
    const int h = wid + hi * 4;
    #pragma unroll
    for (int dt = 0; dt < 2; ++dt)
      #pragma unroll
      for (int mt = 0; mt < 4; ++mt) {
        short4v pk;
        #pragma unroll
        for (int r = 0; r < 4; ++r) pk[r] = (short)f2bf(otk[hi][dt][mt][r]);
        *(short4v*)&ob[(mt * 16 + lq) * 264 + h * 32 + dt * 16 + lg * 4] = pk;
      }
  }
  __syncthreads();

  // ---- proj: out = ob · Wp^T + b (wave w -> cols [w*64, w*64+64)) ----
  {
    f32x4 acc[4][4];
    #pragma unroll
    for (int mt = 0; mt < 4; ++mt)
      #pragma unroll
      for (int nt = 0; nt < 4; ++nt) acc[mt][nt] = fz;
    const int c0 = wid * 64;
    #pragma unroll 2
    for (int ks = 0; ks < 8; ++ks) {
      const int k0 = ks * 32;
      bf16x8 a[4], b[4];
      #pragma unroll
      for (int mt = 0; mt < 4; ++mt)
        a[mt] = *(const bf16x8*)&ob[(mt * 16 + lq) * 264 + k0 + lg * 8];
      #pragma unroll
      for (int nt = 0; nt < 4; ++nt)
        b[nt] = *(const bf16x8*)&wproj[(c0 + nt * 16 + lq) * 256 + k0 + lg * 8];
      #pragma unroll
      for (int mt = 0; mt < 4; ++mt)
        #pragma unroll
        for (int nt = 0; nt < 4; ++nt)
          acc[mt][nt] = __builtin_amdgcn_mfma_f32_16x16x32_bf16(a[mt], b[nt], acc[mt][nt], 0, 0, 0);
    }
    #pragma unroll
    for (int nt = 0; nt < 4; ++nt) {
      const float pbv = projb[c0 + nt * 16 + lq];
      #pragma unroll
      for (int mt = 0; mt < 4; ++mt)
        #pragma unroll
        for (int r = 0; r < 4; ++r) {
          const int row = mt * 16 + lg * 4 + r;
          out[((size_t)blk * 64 + row) * 256 + c0 + nt * 16 + lq] = acc[mt][nt][r] + pbv;
        }
    }
  }
}

extern "C" void kernel_launch(void* const* d_in, const int* in_sizes, int n_in,
                              void* d_out, int out_size, void* d_ws, size_t ws_size,
                              hipStream_t stream) {
  const float* x     = (const float*)d_in[0];
  const float* qkvw  = (const float*)d_in[1];
  const float* qbias = (const float*)d_in[2];
  const float* vbias = (const float*)d_in[3];
  const float* ls    = (const float*)d_in[4];
  const float* w1    = (const float*)d_in[5];
  const float* b1    = (const float*)d_in[6];
  const float* w2    = (const float*)d_in[7];
  const float* pw    = (const float*)d_in[8];
  const float* pbias = (const float*)d_in[9];
  float* out = (float*)d_out;

  char* ws = (char*)d_ws;
  short* wqkv_bf  = (short*)(ws);                 // 393216 B
  short* wproj_bf = (short*)(ws + 393216);        // 131072 B
  float* rpb      = (float*)(ws + 524288);        // 131072 B
  float* scale    = (float*)(ws + 655360);        // 32 B
  float* qkvb     = (float*)(ws + 655392);        // 3072 B
  float* bt       = (float*)(ws + 658464);        // 4064 B

  cpb_table_kernel<<<dim3(127), dim3(64), 0, stream>>>(w1, b1, w2, bt);
  cpb_expand_kernel<<<dim3(128), dim3(256), 0, stream>>>(bt, ls, rpb, scale);
  convert_kernel<<<dim3(1024), dim3(256), 0, stream>>>(qkvw, pw, qbias, vbias,
                                                       wqkv_bf, wproj_bf, qkvb);
  win_attn_kernel<<<dim3(2048), dim3(256), 0, stream>>>(x, wqkv_bf, wproj_bf, qkvb,
                                                        scale, rpb, pbias, out);
}

// Round 9
// 289.465 us; speedup vs baseline: 1.3652x; 1.3652x over previous
//
#include <hip/hip_runtime.h>
#include <hip/hip_bf16.h>

// Swin-V2 window attention, fused. B=2048 windows, N=64 tokens, C=256, H=8, Dh=32.
// R9 = Round-2's PASSING win_attn_kernel verbatim (f2bf for all accumulator
// packs; cvt2 ONLY on the x-staging load path) + parallel split cpb.
// R8 lessons: deferred-V regressed (x re-read thrashes L2: FETCH +62MB, dur +33%);
// occupancy stuck at 2 blocks/CU even at 51,200 B LDS (usable-LDS cap ~128 KiB).
//   cpb_table_kernel:  CPB MLP -> bias table bt[127][8] (127 blocks, wave-parallel).
//   cpb_expand_kernel: bt -> 16*sigmoid in MFMA C-frag layout; scale[h].
//   convert_kernel:    qkv_weight/proj_w -> bf16; concat qkv bias.
//   win_attn_kernel:   1 block/window, 4 waves, wave owns heads {w, w+4}.
//     x frags from global f32 + cvt2 (L1/L2 reuse), QKV GEMMs -> q/k/v epilogues
//     -> per-wave LDS, QK^T + bias + softmax -> P, PV -> regs (otk);
//     barrier, otk -> ob via f2bf (overlays wbuf), barrier, proj GEMM.
//   LDS = 59,392 B -> 2 blocks/CU.
// mfma_f32_16x16x32_bf16; C/D: col=lane&15, row=(lane>>4)*4+reg;
// A/B frag: M[lane&15][(lane>>4)*8 + j] (contiguous 8 bf16 = 16B ds_read_b128).
// RULE (hard-won, R3..R8): never feed MFMA accumulator values to inline-asm
// v_cvt_pk_bf16_f32 — silently wrong results (0.119 absmax) or NaN under
// launch_bounds>=3 register pressure. f2bf (pure C bit-ops) is always safe.

typedef __attribute__((ext_vector_type(8))) short bf16x8;
typedef __attribute__((ext_vector_type(4))) short short4v;
typedef __attribute__((ext_vector_type(4))) float f32x4;

__device__ __forceinline__ unsigned short f2bf(float f) {
  union { float f; unsigned int u; } a; a.f = f;
  return (unsigned short)((a.u + 0x7FFFu + ((a.u >> 16) & 1u)) >> 16);  // RNE
}

// packed f32x2 -> bf16x2, single VALU instr; elem0 in low half.
// ONLY safe on plain-VGPR values (global-load results) — see RULE above.
__device__ __forceinline__ unsigned int cvt2(float lo, float hi) {
  unsigned int r;
  asm("v_cvt_pk_bf16_f32 %0, %1, %2" : "=v"(r) : "v"(lo), "v"(hi));
  return r;
}

// ---------------- CPB MLP table: bt[row][h] (parallel) ----------------
__global__ void cpb_table_kernel(const float* __restrict__ w1, const float* __restrict__ b1,
                                 const float* __restrict__ w2, float* __restrict__ bt)
{
  const int row = blockIdx.x;       // 0..126
  const int lane = threadIdx.x;     // 0..63
  float xr = ((float)row - 63.0f) * (8.0f / 63.0f);
  float sgn = (xr > 0.0f) ? 1.0f : ((xr < 0.0f) ? -1.0f : 0.0f);
  float val = sgn * log2f(fabsf(xr) + 1.0f) * (1.0f / 3.0f);  // /log2(8)
  float acc[8];
  #pragma unroll
  for (int hh = 0; hh < 8; ++hh) acc[hh] = 0.0f;
  #pragma unroll
  for (int jj = 0; jj < 8; ++jj) {
    int j = jj * 64 + lane;
    float hv = fmaxf(val * w1[j] + b1[j], 0.0f);
    #pragma unroll
    for (int hh = 0; hh < 8; ++hh) acc[hh] += hv * w2[hh * 512 + j];
  }
  #pragma unroll
  for (int hh = 0; hh < 8; ++hh) {
    #pragma unroll
    for (int m = 1; m < 64; m <<= 1) acc[hh] += __shfl_xor(acc[hh], m);
  }
  if (lane == 0) {
    #pragma unroll
    for (int hh = 0; hh < 8; ++hh) bt[row * 8 + hh] = acc[hh];
  }
}

// ---- expand: rpb[h][mt][nt][lane][r] = 16*sigmoid(bt[row-col+63][h]); scale[h] ----
__global__ void cpb_expand_kernel(const float* __restrict__ bt, const float* __restrict__ ls,
                                  float* __restrict__ rpb, float* __restrict__ scale)
{
  const int i = blockIdx.x * 256 + threadIdx.x;   // 0..32767
  int r = i & 3, lane = (i >> 2) & 63, nt = (i >> 8) & 3, mt = (i >> 10) & 3, hh = i >> 12;
  int row = mt * 16 + (lane >> 4) * 4 + r;
  int col = nt * 16 + (lane & 15);
  float b = bt[(row - col + 63) * 8 + hh];
  rpb[i] = 16.0f / (1.0f + __expf(-b));
  if (i < 8) scale[i] = __expf(fminf(ls[i], 4.605170185988091f));  // ln(100)
}

// ---------------- weight conversion (proven verbatim) ----------------
__global__ void convert_kernel(const float* __restrict__ qw, const float* __restrict__ pw,
                               const float* __restrict__ qb, const float* __restrict__ vb,
                               short* __restrict__ wqkv, short* __restrict__ wproj,
                               float* __restrict__ qkvb)
{
  const int idx = blockIdx.x * 256 + threadIdx.x;
  if (idx < 196608) wqkv[idx] = (short)f2bf(qw[idx]);
  else if (idx - 196608 < 65536) wproj[idx - 196608] = (short)f2bf(pw[idx - 196608]);
  if (idx < 768) qkvb[idx] = (idx < 256) ? qb[idx] : ((idx < 512) ? 0.0f : vb[idx - 512]);
}

// ---------------- fused window attention (Round-2 PASSING version verbatim) ----------------
__global__ __launch_bounds__(256, 2) void win_attn_kernel(
    const float* __restrict__ x,
    const short* __restrict__ wqkv,
    const short* __restrict__ wproj,
    const float* __restrict__ qkvb,
    const float* __restrict__ scale,
    const float* __restrict__ rpb,
    const float* __restrict__ projb,
    float* __restrict__ out)
{
  __shared__ short wbuf[4][7424];   // per wave: q[0:2560) s40, k[2560:5120) s40,
                                    // vt[5120:7424) s72; P overlays [0:4608) s72.
                                    // ob (stride 264, 33,792 B) overlays wbuf after barrier.

  const int tid = threadIdx.x;
  const int wid = tid >> 6;
  const int lane = tid & 63;
  const int lq = lane & 15;
  const int lg = lane >> 4;
  const int blk = blockIdx.x;

  short* qb  = wbuf[wid];
  short* kb  = qb + 2560;
  short* vtb = qb + 5120;
  short* pb  = qb;
  short* ob  = &wbuf[0][0];

  const f32x4 fz = {0.0f, 0.0f, 0.0f, 0.0f};
  const float* xbase = x + ((size_t)blk * 64 + lq) * 256 + lg * 8;

  f32x4 otk[2][2][4];   // [hi][dt][mt], hi is compile-time (loop unrolled)

  #pragma unroll
  for (int hi = 0; hi < 2; ++hi) {
    const int h = wid + hi * 4;

    // ---- QKV: sq/sk = W · x^T (q^T,k^T C-layout), sv = x · Wv^T (v C-layout) ----
    f32x4 sq[2][4], sk[2][4], sv[4][2];
    #pragma unroll
    for (int i = 0; i < 2; ++i)
      #pragma unroll
      for (int j = 0; j < 4; ++j) { sq[i][j] = fz; sk[i][j] = fz; sv[j][i] = fz; }

    const short* wqb = wqkv + (h * 32 + lq) * 256 + lg * 8;

    #pragma unroll 2
    for (int ks = 0; ks < 8; ++ks) {
      const int k0 = ks * 32;
      bf16x8 xf[4];
      #pragma unroll
      for (int mt = 0; mt < 4; ++mt) {
        const float* xp = xbase + mt * 4096 + k0;
        float4 a = *(const float4*)xp;
        float4 b = *(const float4*)(xp + 4);
        union { unsigned int u[4]; bf16x8 v; } c;
        c.u[0] = cvt2(a.x, a.y); c.u[1] = cvt2(a.z, a.w);
        c.u[2] = cvt2(b.x, b.y); c.u[3] = cvt2(b.z, b.w);
        xf[mt] = c.v;
      }
      bf16x8 wqf[2], wkf[2], wvf[2];
      #pragma unroll
      for (int dt = 0; dt < 2; ++dt) {
        const short* wp = wqb + dt * 4096 + k0;
        wqf[dt] = *(const bf16x8*)wp;
        wkf[dt] = *(const bf16x8*)(wp + 65536);    // +256 rows
        wvf[dt] = *(const bf16x8*)(wp + 131072);   // +512 rows
      }
      #pragma unroll
      for (int dt = 0; dt < 2; ++dt)
        #pragma unroll
        for (int mt = 0; mt < 4; ++mt) {
          sq[dt][mt] = __builtin_amdgcn_mfma_f32_16x16x32_bf16(wqf[dt], xf[mt], sq[dt][mt], 0, 0, 0);
          sk[dt][mt] = __builtin_amdgcn_mfma_f32_16x16x32_bf16(wkf[dt], xf[mt], sk[dt][mt], 0, 0, 0);
          sv[mt][dt] = __builtin_amdgcn_mfma_f32_16x16x32_bf16(xf[mt], wvf[dt], sv[mt][dt], 0, 0, 0);
        }
    }

    // ---- q epilogue: +bias, L2-normalize rows, packed store [token][d] ----
    {
      float qbias[2][4];
      #pragma unroll
      for (int dt = 0; dt < 2; ++dt)
        #pragma unroll
        for (int r = 0; r < 4; ++r)
          qbias[dt][r] = qkvb[h * 32 + dt * 16 + lg * 4 + r];
      #pragma unroll
      for (int mt = 0; mt < 4; ++mt) {
        float vv[2][4];
        float ss = 0.0f;
        #pragma unroll
        for (int dt = 0; dt < 2; ++dt)
          #pragma unroll
          for (int r = 0; r < 4; ++r) {
            vv[dt][r] = sq[dt][mt][r] + qbias[dt][r];
            ss += vv[dt][r] * vv[dt][r];
          }
        ss += __shfl_xor(ss, 16);
        ss += __shfl_xor(ss, 32);
        float rn = 1.0f / fmaxf(sqrtf(ss), 1e-12f);
        #pragma unroll
        for (int dt = 0; dt < 2; ++dt) {
          short4v pk;
          #pragma unroll
          for (int r = 0; r < 4; ++r) pk[r] = (short)f2bf(vv[dt][r] * rn);
          *(short4v*)&qb[(mt * 16 + lq) * 40 + dt * 16 + lg * 4] = pk;
        }
      }
    }
    // ---- k epilogue (bias = 0) ----
    {
      #pragma unroll
      for (int mt = 0; mt < 4; ++mt) {
        float ss = 0.0f;
        #pragma unroll
        for (int dt = 0; dt < 2; ++dt)
          #pragma unroll
          for (int r = 0; r < 4; ++r) ss += sk[dt][mt][r] * sk[dt][mt][r];
        ss += __shfl_xor(ss, 16);
        ss += __shfl_xor(ss, 32);
        float rn = 1.0f / fmaxf(sqrtf(ss), 1e-12f);
        #pragma unroll
        for (int dt = 0; dt < 2; ++dt) {
          short4v pk;
          #pragma unroll
          for (int r = 0; r < 4; ++r) pk[r] = (short)f2bf(sk[dt][mt][r] * rn);
          *(short4v*)&kb[(mt * 16 + lq) * 40 + dt * 16 + lg * 4] = pk;
        }
      }
    }
    // ---- v epilogue: +bias, packed transposed store v^T[d][token] ----
    {
      float vb0 = qkvb[512 + h * 32 + lq];
      float vb1 = qkvb[512 + h * 32 + 16 + lq];
      #pragma unroll
      for (int mt = 0; mt < 4; ++mt) {
        short4v p0, p1;
        #pragma unroll
        for (int r = 0; r < 4; ++r) {
          p0[r] = (short)f2bf(sv[mt][0][r] + vb0);
          p1[r] = (short)f2bf(sv[mt][1][r] + vb1);
        }
        *(short4v*)&vtb[lq * 72 + mt * 16 + lg * 4] = p0;
        *(short4v*)&vtb[(16 + lq) * 72 + mt * 16 + lg * 4] = p1;
      }
    }

    // ---- QK^T (K=32, single k-step) ----
    f32x4 s[4][4];
    {
      bf16x8 a2[4], b2[4];
      #pragma unroll
      for (int mt = 0; mt < 4; ++mt)
        a2[mt] = *(const bf16x8*)&qb[(mt * 16 + lq) * 40 + lg * 8];
      #pragma unroll
      for (int nt = 0; nt < 4; ++nt)
        b2[nt] = *(const bf16x8*)&kb[(nt * 16 + lq) * 40 + lg * 8];
      #pragma unroll
      for (int mt = 0; mt < 4; ++mt)
        #pragma unroll
        for (int nt = 0; nt < 4; ++nt)
          s[mt][nt] = __builtin_amdgcn_mfma_f32_16x16x32_bf16(a2[mt], b2[nt], fz, 0, 0, 0);
    }

    // ---- softmax (scale, +rpb, rowwise over 64 cols) -> P bf16 in LDS ----
    const float sch = scale[h];
    #pragma unroll
    for (int mt = 0; mt < 4; ++mt) {
      f32x4 rp[4];
      #pragma unroll
      for (int nt = 0; nt < 4; ++nt)
        rp[nt] = ((const f32x4*)rpb)[((h * 4 + mt) * 4 + nt) * 64 + lane];
      #pragma unroll
      for (int r = 0; r < 4; ++r) {
        float v0 = s[mt][0][r] * sch + rp[0][r];
        float v1 = s[mt][1][r] * sch + rp[1][r];
        float v2 = s[mt][2][r] * sch + rp[2][r];
        float v3 = s[mt][3][r] * sch + rp[3][r];
        float mx = fmaxf(fmaxf(v0, v1), fmaxf(v2, v3));
        mx = fmaxf(mx, __shfl_xor(mx, 1));
        mx = fmaxf(mx, __shfl_xor(mx, 2));
        mx = fmaxf(mx, __shfl_xor(mx, 4));
        mx = fmaxf(mx, __shfl_xor(mx, 8));
        float e0 = __expf(v0 - mx);
        float e1 = __expf(v1 - mx);
        float e2 = __expf(v2 - mx);
        float e3 = __expf(v3 - mx);
        float sm = e0 + e1 + e2 + e3;
        sm += __shfl_xor(sm, 1);
        sm += __shfl_xor(sm, 2);
        sm += __shfl_xor(sm, 4);
        sm += __shfl_xor(sm, 8);
        float inv = 1.0f / sm;
        const int row = mt * 16 + lg * 4 + r;
        pb[row * 72 + lq]      = (short)f2bf(e0 * inv);
        pb[row * 72 + 16 + lq] = (short)f2bf(e1 * inv);
        pb[row * 72 + 32 + lq] = (short)f2bf(e2 * inv);
        pb[row * 72 + 48 + lq] = (short)f2bf(e3 * inv);
      }
    }

    // ---- PV: out^T = v^T · P^T -> registers (otk) ----
    #pragma unroll
    for (int dt = 0; dt < 2; ++dt)
      #pragma unroll
      for (int mt = 0; mt < 4; ++mt) otk[hi][dt][mt] = fz;
    #pragma unroll
    for (int kt = 0; kt < 2; ++kt) {
      bf16x8 av2[2], bp[4];
      #pragma unroll
      for (int dt = 0; dt < 2; ++dt)
        av2[dt] = *(const bf16x8*)&vtb[(dt * 16 + lq) * 72 + kt * 32 + lg * 8];
      #pragma unroll
      for (int mt = 0; mt < 4; ++mt)
        bp[mt] = *(const bf16x8*)&pb[(mt * 16 + lq) * 72 + kt * 32 + lg * 8];
      #pragma unroll
      for (int dt = 0; dt < 2; ++dt)
        #pragma unroll
        for (int mt = 0; mt < 4; ++mt)
          otk[hi][dt][mt] = __builtin_amdgcn_mfma_f32_16x16x32_bf16(av2[dt], bp[mt], otk[hi][dt][mt], 0, 0, 0);
    }
  }  // hi

  // ---- all waves done with private buffers: overlay ob on wbuf (f2bf pack) ----
  __syncthreads();
  #pragma unroll
  for (int hi = 0; hi < 2; ++hi) {
    const int h = wid + hi * 4;
    #pragma unroll
    for (int dt = 0; dt < 2; ++dt)
      #pragma unroll
      for (int mt = 0; mt < 4; ++mt) {
        short4v pk;
        #pragma unroll
        for (int r = 0; r < 4; ++r) pk[r] = (short)f2bf(otk[hi][dt][mt][r]);
        *(short4v*)&ob[(mt * 16 + lq) * 264 + h * 32 + dt * 16 + lg * 4] = pk;
      }
  }
  __syncthreads();

  // ---- proj: out = ob · Wp^T + b (wave w -> cols [w*64, w*64+64)) ----
  {
    f32x4 acc[4][4];
    #pragma unroll
    for (int mt = 0; mt < 4; ++mt)
      #pragma unroll
      for (int nt = 0; nt < 4; ++nt) acc[mt][nt] = fz;
    const int c0 = wid * 64;
    #pragma unroll 2
    for (int ks = 0; ks < 8; ++ks) {
      const int k0 = ks * 32;
      bf16x8 a[4], b[4];
      #pragma unroll
      for (int mt = 0; mt < 4; ++mt)
        a[mt] = *(const bf16x8*)&ob[(mt * 16 + lq) * 264 + k0 + lg * 8];
      #pragma unroll
      for (int nt = 0; nt < 4; ++nt)
        b[nt] = *(const bf16x8*)&wproj[(c0 + nt * 16 + lq) * 256 + k0 + lg * 8];
      #pragma unroll
      for (int mt = 0; mt < 4; ++mt)
        #pragma unroll
        for (int nt = 0; nt < 4; ++nt)
          acc[mt][nt] = __builtin_amdgcn_mfma_f32_16x16x32_bf16(a[mt], b[nt], acc[mt][nt], 0, 0, 0);
    }
    #pragma unroll
    for (int nt = 0; nt < 4; ++nt) {
      const float pbv = projb[c0 + nt * 16 + lq];
      #pragma unroll
      for (int mt = 0; mt < 4; ++mt)
        #pragma unroll
        for (int r = 0; r < 4; ++r) {
          const int row = mt * 16 + lg * 4 + r;
          out[((size_t)blk * 64 + row) * 256 + c0 + nt * 16 + lq] = acc[mt][nt][r] + pbv;
        }
    }
  }
}

extern "C" void kernel_launch(void* const* d_in, const int* in_sizes, int n_in,
                              void* d_out, int out_size, void* d_ws, size_t ws_size,
                              hipStream_t stream) {
  const float* x     = (const float*)d_in[0];
  const float* qkvw  = (const float*)d_in[1];
  const float* qbias = (const float*)d_in[2];
  const float* vbias = (const float*)d_in[3];
  const float* ls    = (const float*)d_in[4];
  const float* w1    = (const float*)d_in[5];
  const float* b1    = (const float*)d_in[6];
  const float* w2    = (const float*)d_in[7];
  const float* pw    = (const float*)d_in[8];
  const float* pbias = (const float*)d_in[9];
  float* out = (float*)d_out;

  char* ws = (char*)d_ws;
  short* wqkv_bf  = (short*)(ws);                 // 393216 B
  short* wproj_bf = (short*)(ws + 393216);        // 131072 B
  float* rpb      = (float*)(ws + 524288);        // 131072 B
  float* scale    = (float*)(ws + 655360);        // 32 B
  float* qkvb     = (float*)(ws + 655392);        // 3072 B
  float* bt       = (float*)(ws + 658464);        // 4064 B

  cpb_table_kernel<<<dim3(127), dim3(64), 0, stream>>>(w1, b1, w2, bt);
  cpb_expand_kernel<<<dim3(128), dim3(256), 0, stream>>>(bt, ls, rpb, scale);
  convert_kernel<<<dim3(1024), dim3(256), 0, stream>>>(qkvw, pw, qbias, vbias,
                                                       wqkv_bf, wproj_bf, qkvb);
  win_attn_kernel<<<dim3(2048), dim3(256), 0, stream>>>(x, wqkv_bf, wproj_bf, qkvb,
                                                        scale, rpb, pbias, out);
}

// Round 10
// 278.933 us; speedup vs baseline: 1.4167x; 1.0378x over previous
//
#include <hip/hip_runtime.h>
#include <hip/hip_bf16.h>

// Swin-V2 window attention, fused. B=2048 windows, N=64 tokens, C=256, H=8, Dh=32.
// R10 = all-register attention core (R3 structure revived) with:
//   - __shfl(ds_bpermute)-based 4x4 cross-lane-group transpose (verified semantics)
//   - f2bf bit-op packs everywhere on accumulator-derived values (R9-proven)
//   - cvt2 inline asm ONLY on the x global-load path (R2-proven)
//   - swapped QK^T: S^T = mfma(kA,qB) -> softmax in-lane (16 vals + shfl 16/32)
//   - per-head ob store (no cross-head register liveness)
//   - LDS = ob only (33,792 B) -> 3 blocks/CU if VGPR <= 170
// EVIDENCE RULES (R3..R9): never feed MFMA-accumulator-derived values to inline-asm
// v_cvt_pk_bf16_f32 (bit-identical 0.119 absmax in R6/R7; NaN under lb>=3).
// f2bf + __shfl on accumulator values are proven safe (R9 PASS).
// Layout algebra (mfma_f32_16x16x32_bf16): C/D: col=lane&15, row=(lane>>4)*4+reg;
// A-frag A[lane&15][(lane>>4)*8+j]; B-frag B[(lane>>4)*8+j][lane&15]; word w of a
// frag = elements {8*(lane>>4)+2w, +2w+1} (lo=even). Cross-group transpose:
// out word w at lane(lq,lg) = in[X=lg>>1][c=w&1] read at lane lq+16*((lg&1)*2+(w>>1)).

typedef __attribute__((ext_vector_type(8))) short bf16x8;
typedef __attribute__((ext_vector_type(4))) short short4v;
typedef __attribute__((ext_vector_type(4))) float f32x4;

__device__ __forceinline__ unsigned short f2bf(float f) {
  union { float f; unsigned int u; } a; a.f = f;
  return (unsigned short)((a.u + 0x7FFFu + ((a.u >> 16) & 1u)) >> 16);  // RNE
}

// pack two f32 -> u32 of 2 bf16 (lo = first) via pure C bit-ops (acc-safe)
__device__ __forceinline__ unsigned pk2(float lo, float hi) {
  return (unsigned)f2bf(lo) | ((unsigned)f2bf(hi) << 16);
}

// packed f32x2 -> bf16x2, single VALU instr. ONLY safe on plain-VGPR load-path
// values — see EVIDENCE RULES above.
__device__ __forceinline__ unsigned int cvt2(float lo, float hi) {
  unsigned int r;
  asm("v_cvt_pk_bf16_f32 %0, %1, %2" : "=v"(r) : "v"(lo), "v"(hi));
  return r;
}

// 4x4 u32 transpose across stride-16 lane groups via ds_bpermute (__shfl).
// in[X][c] at lane(lq,lg') holds element-pairs {X*16+lg'*4+2c, +2c+1} (col lq);
// out word w at lane(lq,lg) = in[lg>>1][w&1] @ lane lq+16*((lg&1)*2+(w>>1)).
__device__ __forceinline__ bf16x8 xposeS(unsigned i00, unsigned i01,
                                         unsigned i10, unsigned i11, int lane) {
  const int lg = lane >> 4;
  const int s0 = (lane & 15) + 32 * (lg & 1);   // source for words 0,1
  const int s1 = s0 + 16;                       // source for words 2,3
  unsigned a00 = __shfl(i00, s0), a01 = __shfl(i01, s0);
  unsigned b00 = __shfl(i10, s0), b01 = __shfl(i11, s0);
  unsigned a02 = __shfl(i00, s1), a03 = __shfl(i01, s1);
  unsigned b02 = __shfl(i10, s1), b03 = __shfl(i11, s1);
  const bool lo = lg < 2;                       // X = lg>>1 selects register
  union { unsigned u[4]; bf16x8 v; } c;
  c.u[0] = lo ? a00 : b00;
  c.u[1] = lo ? a01 : b01;
  c.u[2] = lo ? a02 : b02;
  c.u[3] = lo ? a03 : b03;
  return c.v;
}

// ---------------- CPB MLP table: bt[row][h] (parallel, R9-proven) ----------------
__global__ void cpb_table_kernel(const float* __restrict__ w1, const float* __restrict__ b1,
                                 const float* __restrict__ w2, float* __restrict__ bt)
{
  const int row = blockIdx.x;       // 0..126
  const int lane = threadIdx.x;     // 0..63
  float xr = ((float)row - 63.0f) * (8.0f / 63.0f);
  float sgn = (xr > 0.0f) ? 1.0f : ((xr < 0.0f) ? -1.0f : 0.0f);
  float val = sgn * log2f(fabsf(xr) + 1.0f) * (1.0f / 3.0f);  // /log2(8)
  float acc[8];
  #pragma unroll
  for (int hh = 0; hh < 8; ++hh) acc[hh] = 0.0f;
  #pragma unroll
  for (int jj = 0; jj < 8; ++jj) {
    int j = jj * 64 + lane;
    float hv = fmaxf(val * w1[j] + b1[j], 0.0f);
    #pragma unroll
    for (int hh = 0; hh < 8; ++hh) acc[hh] += hv * w2[hh * 512 + j];
  }
  #pragma unroll
  for (int hh = 0; hh < 8; ++hh) {
    #pragma unroll
    for (int m = 1; m < 64; m <<= 1) acc[hh] += __shfl_xor(acc[hh], m);
  }
  if (lane == 0) {
    #pragma unroll
    for (int hh = 0; hh < 8; ++hh) bt[row * 8 + hh] = acc[hh];
  }
}

// ---- expand (S^T orientation): rpb[h][mt][nt][lane][r] = 16*sigmoid(bias) ----
// S^T element at lane: row(key) = nt*16+(lane>>4)*4+r, col(query) = mt*16+(lane&15).
__global__ void cpb_expand_kernel(const float* __restrict__ bt, const float* __restrict__ ls,
                                  float* __restrict__ rpb, float* __restrict__ scale)
{
  const int i = blockIdx.x * 256 + threadIdx.x;   // 0..32767
  const int r = i & 3, lane = (i >> 2) & 63, nt = (i >> 8) & 3, mt = (i >> 10) & 3, hh = i >> 12;
  const int row_i = mt * 16 + (lane & 15);          // query index
  const int col_j = nt * 16 + (lane >> 4) * 4 + r;  // key index
  float b = bt[(row_i - col_j + 63) * 8 + hh];
  rpb[i] = 16.0f / (1.0f + __expf(-b));
  if (i < 8) scale[i] = __expf(fminf(ls[i], 4.605170185988091f));  // ln(100)
}

// ---------------- weight conversion (proven verbatim) ----------------
__global__ void convert_kernel(const float* __restrict__ qw, const float* __restrict__ pw,
                               const float* __restrict__ qb, const float* __restrict__ vb,
                               short* __restrict__ wqkv, short* __restrict__ wproj,
                               float* __restrict__ qkvb)
{
  const int idx = blockIdx.x * 256 + threadIdx.x;
  if (idx < 196608) wqkv[idx] = (short)f2bf(qw[idx]);
  else if (idx - 196608 < 65536) wproj[idx - 196608] = (short)f2bf(pw[idx - 196608]);
  if (idx < 768) qkvb[idx] = (idx < 256) ? qb[idx] : ((idx < 512) ? 0.0f : vb[idx - 512]);
}

// ---------------- fused window attention ----------------
__global__ __launch_bounds__(256, 2) void win_attn_kernel(
    const float* __restrict__ x,
    const short* __restrict__ wqkv,
    const short* __restrict__ wproj,
    const float* __restrict__ qkvb,
    const float* __restrict__ scale,
    const float* __restrict__ rpb,
    const float* __restrict__ projb,
    float* __restrict__ out)
{
  __shared__ short ob[64 * 264];   // ONLY LDS: attention output tile [token][C], stride 264

  const int tid = threadIdx.x;
  const int wid = tid >> 6;
  const int lane = tid & 63;
  const int lq = lane & 15;
  const int lg = lane >> 4;
  const int blk = blockIdx.x;

  const f32x4 fz = {0.0f, 0.0f, 0.0f, 0.0f};
  const float* xbase = x + ((size_t)blk * 64 + lq) * 256 + lg * 8;

  #pragma unroll
  for (int hi = 0; hi < 2; ++hi) {
    const int h = wid + hi * 4;
    const short* wqb = wqkv + (h * 32 + lq) * 256 + lg * 8;

    // ---- QKV: sq/sk = W · x^T (q^T,k^T C-layout), sv = x · Wv^T (v C-layout) ----
    f32x4 sq[2][4], sk[2][4], sv[4][2];
    #pragma unroll
    for (int i = 0; i < 2; ++i)
      #pragma unroll
      for (int j = 0; j < 4; ++j) { sq[i][j] = fz; sk[i][j] = fz; sv[j][i] = fz; }

    #pragma unroll 2
    for (int ks = 0; ks < 8; ++ks) {
      const int k0 = ks * 32;
      bf16x8 xf[4];
      #pragma unroll
      for (int mt = 0; mt < 4; ++mt) {
        const float* xp = xbase + mt * 4096 + k0;
        float4 a = *(const float4*)xp;
        float4 b = *(const float4*)(xp + 4);
        union { unsigned int u[4]; bf16x8 v; } c;
        c.u[0] = cvt2(a.x, a.y); c.u[1] = cvt2(a.z, a.w);
        c.u[2] = cvt2(b.x, b.y); c.u[3] = cvt2(b.z, b.w);
        xf[mt] = c.v;
      }
      bf16x8 wqf[2], wkf[2], wvf[2];
      #pragma unroll
      for (int dt = 0; dt < 2; ++dt) {
        const short* wp = wqb + dt * 4096 + k0;
        wqf[dt] = *(const bf16x8*)wp;
        wkf[dt] = *(const bf16x8*)(wp + 65536);    // +256 rows
        wvf[dt] = *(const bf16x8*)(wp + 131072);   // +512 rows
      }
      #pragma unroll
      for (int dt = 0; dt < 2; ++dt)
        #pragma unroll
        for (int mt = 0; mt < 4; ++mt) {
          sq[dt][mt] = __builtin_amdgcn_mfma_f32_16x16x32_bf16(wqf[dt], xf[mt], sq[dt][mt], 0, 0, 0);
          sk[dt][mt] = __builtin_amdgcn_mfma_f32_16x16x32_bf16(wkf[dt], xf[mt], sk[dt][mt], 0, 0, 0);
          sv[mt][dt] = __builtin_amdgcn_mfma_f32_16x16x32_bf16(xf[mt], wvf[dt], sv[mt][dt], 0, 0, 0);
        }
    }

    bf16x8 qB[4], kA[4], vA[2][2];

    // ---- q: +bias, L2-normalize over d (in-lane 8 + shfl 16/32), pack -> B-frags ----
    {
      float qbias[2][4];
      #pragma unroll
      for (int dt = 0; dt < 2; ++dt)
        #pragma unroll
        for (int r = 0; r < 4; ++r)
          qbias[dt][r] = qkvb[h * 32 + dt * 16 + lg * 4 + r];
      #pragma unroll
      for (int mt = 0; mt < 4; ++mt) {
        float vv[2][4];
        float ss = 0.0f;
        #pragma unroll
        for (int dt = 0; dt < 2; ++dt)
          #pragma unroll
          for (int r = 0; r < 4; ++r) {
            vv[dt][r] = sq[dt][mt][r] + qbias[dt][r];
            ss += vv[dt][r] * vv[dt][r];
          }
        ss += __shfl_xor(ss, 16);
        ss += __shfl_xor(ss, 32);
        float rn = 1.0f / fmaxf(sqrtf(ss), 1e-12f);
        qB[mt] = xposeS(pk2(vv[0][0] * rn, vv[0][1] * rn), pk2(vv[0][2] * rn, vv[0][3] * rn),
                        pk2(vv[1][0] * rn, vv[1][1] * rn), pk2(vv[1][2] * rn, vv[1][3] * rn), lane);
      }
    }
    // ---- k: L2-normalize (bias 0), pack -> A-frags ----
    {
      #pragma unroll
      for (int nt = 0; nt < 4; ++nt) {
        float ss = 0.0f;
        #pragma unroll
        for (int dt = 0; dt < 2; ++dt)
          #pragma unroll
          for (int r = 0; r < 4; ++r) ss += sk[dt][nt][r] * sk[dt][nt][r];
        ss += __shfl_xor(ss, 16);
        ss += __shfl_xor(ss, 32);
        float rn = 1.0f / fmaxf(sqrtf(ss), 1e-12f);
        kA[nt] = xposeS(pk2(sk[0][nt][0] * rn, sk[0][nt][1] * rn), pk2(sk[0][nt][2] * rn, sk[0][nt][3] * rn),
                        pk2(sk[1][nt][0] * rn, sk[1][nt][1] * rn), pk2(sk[1][nt][2] * rn, sk[1][nt][3] * rn), lane);
      }
    }
    // ---- v: +bias, pack -> v^T A-frags vA[dt][kt] ----
    {
      const float vb0 = qkvb[512 + h * 32 + lq];
      const float vb1 = qkvb[512 + h * 32 + 16 + lq];
      unsigned vp[4][2][2];
      #pragma unroll
      for (int mt = 0; mt < 4; ++mt) {
        vp[mt][0][0] = pk2(sv[mt][0][0] + vb0, sv[mt][0][1] + vb0);
        vp[mt][0][1] = pk2(sv[mt][0][2] + vb0, sv[mt][0][3] + vb0);
        vp[mt][1][0] = pk2(sv[mt][1][0] + vb1, sv[mt][1][1] + vb1);
        vp[mt][1][1] = pk2(sv[mt][1][2] + vb1, sv[mt][1][3] + vb1);
      }
      #pragma unroll
      for (int dt = 0; dt < 2; ++dt)
        #pragma unroll
        for (int kt = 0; kt < 2; ++kt)
          vA[dt][kt] = xposeS(vp[2 * kt][dt][0], vp[2 * kt][dt][1],
                              vp[2 * kt + 1][dt][0], vp[2 * kt + 1][dt][1], lane);
    }

    // ---- S^T[key][query] = mfma(kA, qB): sT[nt][mt], row=key(lg,r), col=query lq ----
    f32x4 sT[4][4];
    #pragma unroll
    for (int nt = 0; nt < 4; ++nt)
      #pragma unroll
      for (int mt = 0; mt < 4; ++mt)
        sT[nt][mt] = __builtin_amdgcn_mfma_f32_16x16x32_bf16(kA[nt], qB[mt], fz, 0, 0, 0);

    // ---- softmax over keys (16 in-lane + shfl 16/32), pack P^T pairs ----
    const float sch = scale[h];
    unsigned pp[4][4][2];   // [mt][nt][c]
    #pragma unroll
    for (int mt = 0; mt < 4; ++mt) {
      f32x4 rp[4];
      #pragma unroll
      for (int nt = 0; nt < 4; ++nt)
        rp[nt] = ((const f32x4*)rpb)[((h * 4 + mt) * 4 + nt) * 64 + lane];
      float ee[4][4];
      float mx = -3.0e38f;
      #pragma unroll
      for (int nt = 0; nt < 4; ++nt)
        #pragma unroll
        for (int r = 0; r < 4; ++r) {
          float vv = sT[nt][mt][r] * sch + rp[nt][r];
          ee[nt][r] = vv;
          mx = fmaxf(mx, vv);
        }
      mx = fmaxf(mx, __shfl_xor(mx, 16));
      mx = fmaxf(mx, __shfl_xor(mx, 32));
      float sm = 0.0f;
      #pragma unroll
      for (int nt = 0; nt < 4; ++nt)
        #pragma unroll
        for (int r = 0; r < 4; ++r) {
          ee[nt][r] = __expf(ee[nt][r] - mx);
          sm += ee[nt][r];
        }
      sm += __shfl_xor(sm, 16);
      sm += __shfl_xor(sm, 32);
      float inv = 1.0f / sm;
      #pragma unroll
      for (int nt = 0; nt < 4; ++nt) {
        pp[mt][nt][0] = pk2(ee[nt][0] * inv, ee[nt][1] * inv);
        pp[mt][nt][1] = pk2(ee[nt][2] * inv, ee[nt][3] * inv);
      }
    }

    // ---- PV: out^T = v^T · P^T (pB via xposeS) ----
    f32x4 ot[2][4];
    #pragma unroll
    for (int dt = 0; dt < 2; ++dt)
      #pragma unroll
      for (int mt = 0; mt < 4; ++mt) ot[dt][mt] = fz;
    #pragma unroll
    for (int kt = 0; kt < 2; ++kt) {
      bf16x8 pB[4];
      #pragma unroll
      for (int mt = 0; mt < 4; ++mt)
        pB[mt] = xposeS(pp[mt][2 * kt][0], pp[mt][2 * kt][1],
                        pp[mt][2 * kt + 1][0], pp[mt][2 * kt + 1][1], lane);
      #pragma unroll
      for (int dt = 0; dt < 2; ++dt)
        #pragma unroll
        for (int mt = 0; mt < 4; ++mt)
          ot[dt][mt] = __builtin_amdgcn_mfma_f32_16x16x32_bf16(vA[dt][kt], pB[mt], ot[dt][mt], 0, 0, 0);
    }

    // ---- store attention output tile for this head (f2bf pack — acc-safe) ----
    #pragma unroll
    for (int dt = 0; dt < 2; ++dt)
      #pragma unroll
      for (int mt = 0; mt < 4; ++mt) {
        short4v pk;
        #pragma unroll
        for (int r = 0; r < 4; ++r) pk[r] = (short)f2bf(ot[dt][mt][r]);
        *(short4v*)&ob[(mt * 16 + lq) * 264 + h * 32 + dt * 16 + lg * 4] = pk;
      }
  }  // hi

  __syncthreads();

  // ---- proj: out = ob · Wp^T + b (wave w -> cols [w*64, w*64+64)) ----
  {
    f32x4 acc[4][4];
    #pragma unroll
    for (int mt = 0; mt < 4; ++mt)
      #pragma unroll
      for (int nt = 0; nt < 4; ++nt) acc[mt][nt] = fz;
    const int c0 = wid * 64;
    #pragma unroll 2
    for (int ks = 0; ks < 8; ++ks) {
      const int k0 = ks * 32;
      bf16x8 a[4], b[4];
      #pragma unroll
      for (int mt = 0; mt < 4; ++mt)
        a[mt] = *(const bf16x8*)&ob[(mt * 16 + lq) * 264 + k0 + lg * 8];
      #pragma unroll
      for (int nt = 0; nt < 4; ++nt)
        b[nt] = *(const bf16x8*)&wproj[(c0 + nt * 16 + lq) * 256 + k0 + lg * 8];
      #pragma unroll
      for (int mt = 0; mt < 4; ++mt)
        #pragma unroll
        for (int nt = 0; nt < 4; ++nt)
          acc[mt][nt] = __builtin_amdgcn_mfma_f32_16x16x32_bf16(a[mt], b[nt], acc[mt][nt], 0, 0, 0);
    }
    #pragma unroll
    for (int nt = 0; nt < 4; ++nt) {
      const float pbv = projb[c0 + nt * 16 + lq];
      #pragma unroll
      for (int mt = 0; mt < 4; ++mt)
        #pragma unroll
        for (int r = 0; r < 4; ++r) {
          const int row = mt * 16 + lg * 4 + r;
          out[((size_t)blk * 64 + row) * 256 + c0 + nt * 16 + lq] = acc[mt][nt][r] + pbv;
        }
    }
  }
}

extern "C" void kernel_launch(void* const* d_in, const int* in_sizes, int n_in,
                              void* d_out, int out_size, void* d_ws, size_t ws_size,
                              hipStream_t stream) {
  const float* x     = (const float*)d_in[0];
  const float* qkvw  = (const float*)d_in[1];
  const float* qbias = (const float*)d_in[2];
  const float* vbias = (const float*)d_in[3];
  const float* ls    = (const float*)d_in[4];
  const float* w1    = (const float*)d_in[5];
  const float* b1    = (const float*)d_in[6];
  const float* w2    = (const float*)d_in[7];
  const float* pw    = (const float*)d_in[8];
  const float* pbias = (const float*)d_in[9];
  float* out = (float*)d_out;

  char* ws = (char*)d_ws;
  short* wqkv_bf  = (short*)(ws);                 // 393216 B
  short* wproj_bf = (short*)(ws + 393216);        // 131072 B
  float* rpb      = (float*)(ws + 524288);        // 131072 B
  float* scale    = (float*)(ws + 655360);        // 32 B
  float* qkvb     = (float*)(ws + 655392);        // 3072 B
  float* bt       = (float*)(ws + 658464);        // 4064 B

  cpb_table_kernel<<<dim3(127), dim3(64), 0, stream>>>(w1, b1, w2, bt);
  cpb_expand_kernel<<<dim3(128), dim3(256), 0, stream>>>(bt, ls, rpb, scale);
  convert_kernel<<<dim3(1024), dim3(256), 0, stream>>>(qkvw, pw, qbias, vbias,
                                                       wqkv_bf, wproj_bf, qkvb);
  win_attn_kernel<<<dim3(2048), dim3(256), 0, stream>>>(x, wqkv_bf, wproj_bf, qkvb,
                                                        scale, rpb, pbias, out);
}

// Round 12
// 191.725 us; speedup vs baseline: 2.0611x; 1.4549x over previous
//
#include <hip/hip_runtime.h>
#include <hip/hip_bf16.h>

// Swin-V2 window attention, fused. B=2048 windows, N=64 tokens, C=256, H=8, Dh=32.
// R12 = R10 all-register core + LDS x-staging (R1's proven layout) + R2's proven
// otk-hold epilogue so the ob write overlays the dead xb region (one 33,792 B
// LDS buffer, no occupancy change).
// EVIDENCE RULES (R3..R11):
//  - never feed MFMA-accumulator-derived values to inline-asm v_cvt_pk_bf16_f32
//    (bit-identical 0.119 absmax R6/R7); f2bf bit-ops are always safe.
//  - never use __launch_bounds__ minWavesPerEU >= 3 (NaN with AND without cvt2:
//    R3/R4/R5/R11); occupancy is register-capped at 2 blocks/CU anyway
//    (arch VGPR + MFMA accumulators > 128 total).
//  - deferred-V x re-read thrashes L2 (R8: +62MB FETCH, +33% dur) — stage instead.
// Layout algebra (mfma_f32_16x16x32_bf16): C/D: col=lane&15, row=(lane>>4)*4+reg;
// A-frag A[lane&15][(lane>>4)*8+j]; B-frag B[(lane>>4)*8+j][lane&15];
// xposeS: out word w at lane(lq,lg) = in[lg>>1][w&1] @ lane lq+16*((lg&1)*2+(w>>1)).

typedef __attribute__((ext_vector_type(8))) short bf16x8;
typedef __attribute__((ext_vector_type(4))) short short4v;
typedef __attribute__((ext_vector_type(4))) float f32x4;

__device__ __forceinline__ unsigned short f2bf(float f) {
  union { float f; unsigned int u; } a; a.f = f;
  return (unsigned short)((a.u + 0x7FFFu + ((a.u >> 16) & 1u)) >> 16);  // RNE
}

// pack two f32 -> u32 of 2 bf16 (lo = first) via pure C bit-ops (acc-safe)
__device__ __forceinline__ unsigned pk2(float lo, float hi) {
  return (unsigned)f2bf(lo) | ((unsigned)f2bf(hi) << 16);
}

// packed f32x2 -> bf16x2, single VALU instr. ONLY safe on plain-VGPR load-path
// values — see EVIDENCE RULES above.
__device__ __forceinline__ unsigned int cvt2(float lo, float hi) {
  unsigned int r;
  asm("v_cvt_pk_bf16_f32 %0, %1, %2" : "=v"(r) : "v"(lo), "v"(hi));
  return r;
}

// 4x4 u32 transpose across stride-16 lane groups via ds_bpermute (__shfl).
// R10-proven (PASS, absmax 0.001953).
__device__ __forceinline__ bf16x8 xposeS(unsigned i00, unsigned i01,
                                         unsigned i10, unsigned i11, int lane) {
  const int lg = lane >> 4;
  const int s0 = (lane & 15) + 32 * (lg & 1);   // source for words 0,1
  const int s1 = s0 + 16;                       // source for words 2,3
  unsigned a00 = __shfl(i00, s0), a01 = __shfl(i01, s0);
  unsigned b00 = __shfl(i10, s0), b01 = __shfl(i11, s0);
  unsigned a02 = __shfl(i00, s1), a03 = __shfl(i01, s1);
  unsigned b02 = __shfl(i10, s1), b03 = __shfl(i11, s1);
  const bool lo = lg < 2;                       // X = lg>>1 selects register
  union { unsigned u[4]; bf16x8 v; } c;
  c.u[0] = lo ? a00 : b00;
  c.u[1] = lo ? a01 : b01;
  c.u[2] = lo ? a02 : b02;
  c.u[3] = lo ? a03 : b03;
  return c.v;
}

// ---------------- CPB MLP table: bt[row][h] (parallel, R9-proven) ----------------
__global__ void cpb_table_kernel(const float* __restrict__ w1, const float* __restrict__ b1,
                                 const float* __restrict__ w2, float* __restrict__ bt)
{
  const int row = blockIdx.x;       // 0..126
  const int lane = threadIdx.x;     // 0..63
  float xr = ((float)row - 63.0f) * (8.0f / 63.0f);
  float sgn = (xr > 0.0f) ? 1.0f : ((xr < 0.0f) ? -1.0f : 0.0f);
  float val = sgn * log2f(fabsf(xr) + 1.0f) * (1.0f / 3.0f);  // /log2(8)
  float acc[8];
  #pragma unroll
  for (int hh = 0; hh < 8; ++hh) acc[hh] = 0.0f;
  #pragma unroll
  for (int jj = 0; jj < 8; ++jj) {
    int j = jj * 64 + lane;
    float hv = fmaxf(val * w1[j] + b1[j], 0.0f);
    #pragma unroll
    for (int hh = 0; hh < 8; ++hh) acc[hh] += hv * w2[hh * 512 + j];
  }
  #pragma unroll
  for (int hh = 0; hh < 8; ++hh) {
    #pragma unroll
    for (int m = 1; m < 64; m <<= 1) acc[hh] += __shfl_xor(acc[hh], m);
  }
  if (lane == 0) {
    #pragma unroll
    for (int hh = 0; hh < 8; ++hh) bt[row * 8 + hh] = acc[hh];
  }
}

// ---- expand (S^T orientation, R10-proven): rpb[h][mt][nt][lane][r] ----
__global__ void cpb_expand_kernel(const float* __restrict__ bt, const float* __restrict__ ls,
                                  float* __restrict__ rpb, float* __restrict__ scale)
{
  const int i = blockIdx.x * 256 + threadIdx.x;   // 0..32767
  const int r = i & 3, lane = (i >> 2) & 63, nt = (i >> 8) & 3, mt = (i >> 10) & 3, hh = i >> 12;
  const int row_i = mt * 16 + (lane & 15);          // query index
  const int col_j = nt * 16 + (lane >> 4) * 4 + r;  // key index
  float b = bt[(row_i - col_j + 63) * 8 + hh];
  rpb[i] = 16.0f / (1.0f + __expf(-b));
  if (i < 8) scale[i] = __expf(fminf(ls[i], 4.605170185988091f));  // ln(100)
}

// ---------------- weight conversion (proven verbatim) ----------------
__global__ void convert_kernel(const float* __restrict__ qw, const float* __restrict__ pw,
                               const float* __restrict__ qb, const float* __restrict__ vb,
                               short* __restrict__ wqkv, short* __restrict__ wproj,
                               float* __restrict__ qkvb)
{
  const int idx = blockIdx.x * 256 + threadIdx.x;
  if (idx < 196608) wqkv[idx] = (short)f2bf(qw[idx]);
  else if (idx - 196608 < 65536) wproj[idx - 196608] = (short)f2bf(pw[idx - 196608]);
  if (idx < 768) qkvb[idx] = (idx < 256) ? qb[idx] : ((idx < 512) ? 0.0f : vb[idx - 512]);
}

// ---------------- fused window attention ----------------
__global__ __launch_bounds__(256, 2) void win_attn_kernel(
    const float* __restrict__ x,
    const short* __restrict__ wqkv,
    const short* __restrict__ wproj,
    const float* __restrict__ qkvb,
    const float* __restrict__ scale,
    const float* __restrict__ rpb,
    const float* __restrict__ projb,
    float* __restrict__ out)
{
  // single 33,792 B buffer: x tile bf16 [token][C] stride 264 during QKV;
  // overlaid by attention-output tile ob (same layout) after the hi loop.
  __shared__ short sbuf[64 * 264];

  const int tid = threadIdx.x;
  const int wid = tid >> 6;
  const int lane = tid & 63;
  const int lq = lane & 15;
  const int lg = lane >> 4;
  const int blk = blockIdx.x;

  const f32x4 fz = {0.0f, 0.0f, 0.0f, 0.0f};

  // ---- stage x tile (64x256 f32 -> bf16 LDS, R1-proven layout; cvt2 on load path) ----
  {
    const int r = tid >> 2;
    const int c0 = (tid & 3) * 64;
    const float4* xg = (const float4*)(x + ((size_t)blk * 64 + r) * 256 + c0);
    short* dst = &sbuf[r * 264 + c0];
    #pragma unroll
    for (int i = 0; i < 16; i += 2) {
      float4 a = xg[i];
      float4 b = xg[i + 1];
      union { unsigned int u[4]; bf16x8 v; } c;
      c.u[0] = cvt2(a.x, a.y); c.u[1] = cvt2(a.z, a.w);
      c.u[2] = cvt2(b.x, b.y); c.u[3] = cvt2(b.z, b.w);
      *(bf16x8*)(dst + i * 4) = c.v;
    }
  }
  __syncthreads();

  f32x4 otk[2][2][4];   // [hi][dt][mt], hi compile-time (R2-proven epilogue hold)

  #pragma unroll
  for (int hi = 0; hi < 2; ++hi) {
    const int h = wid + hi * 4;
    const short* wqb = wqkv + (h * 32 + lq) * 256 + lg * 8;

    // ---- QKV: sq/sk = W · x^T (q^T,k^T C-layout), sv = x · Wv^T (v C-layout) ----
    f32x4 sq[2][4], sk[2][4], sv[4][2];
    #pragma unroll
    for (int i = 0; i < 2; ++i)
      #pragma unroll
      for (int j = 0; j < 4; ++j) { sq[i][j] = fz; sk[i][j] = fz; sv[j][i] = fz; }

    #pragma unroll 2
    for (int ks = 0; ks < 8; ++ks) {
      const int k0 = ks * 32;
      bf16x8 xf[4];
      #pragma unroll
      for (int mt = 0; mt < 4; ++mt)
        xf[mt] = *(const bf16x8*)&sbuf[(mt * 16 + lq) * 264 + k0 + lg * 8];
      bf16x8 wqf[2], wkf[2], wvf[2];
      #pragma unroll
      for (int dt = 0; dt < 2; ++dt) {
        const short* wp = wqb + dt * 4096 + k0;
        wqf[dt] = *(const bf16x8*)wp;
        wkf[dt] = *(const bf16x8*)(wp + 65536);    // +256 rows
        wvf[dt] = *(const bf16x8*)(wp + 131072);   // +512 rows
      }
      #pragma unroll
      for (int dt = 0; dt < 2; ++dt)
        #pragma unroll
        for (int mt = 0; mt < 4; ++mt) {
          sq[dt][mt] = __builtin_amdgcn_mfma_f32_16x16x32_bf16(wqf[dt], xf[mt], sq[dt][mt], 0, 0, 0);
          sk[dt][mt] = __builtin_amdgcn_mfma_f32_16x16x32_bf16(wkf[dt], xf[mt], sk[dt][mt], 0, 0, 0);
          sv[mt][dt] = __builtin_amdgcn_mfma_f32_16x16x32_bf16(xf[mt], wvf[dt], sv[mt][dt], 0, 0, 0);
        }
    }

    bf16x8 qB[4], kA[4], vA[2][2];

    // ---- q: +bias, L2-normalize over d (in-lane 8 + shfl 16/32), pack -> B-frags ----
    {
      float qbias[2][4];
      #pragma unroll
      for (int dt = 0; dt < 2; ++dt)
        #pragma unroll
        for (int r = 0; r < 4; ++r)
          qbias[dt][r] = qkvb[h * 32 + dt * 16 + lg * 4 + r];
      #pragma unroll
      for (int mt = 0; mt < 4; ++mt) {
        float vv[2][4];
        float ss = 0.0f;
        #pragma unroll
        for (int dt = 0; dt < 2; ++dt)
          #pragma unroll
          for (int r = 0; r < 4; ++r) {
            vv[dt][r] = sq[dt][mt][r] + qbias[dt][r];
            ss += vv[dt][r] * vv[dt][r];
          }
        ss += __shfl_xor(ss, 16);
        ss += __shfl_xor(ss, 32);
        float rn = 1.0f / fmaxf(sqrtf(ss), 1e-12f);
        qB[mt] = xposeS(pk2(vv[0][0] * rn, vv[0][1] * rn), pk2(vv[0][2] * rn, vv[0][3] * rn),
                        pk2(vv[1][0] * rn, vv[1][1] * rn), pk2(vv[1][2] * rn, vv[1][3] * rn), lane);
      }
    }
    // ---- k: L2-normalize (bias 0), pack -> A-frags ----
    {
      #pragma unroll
      for (int nt = 0; nt < 4; ++nt) {
        float ss = 0.0f;
        #pragma unroll
        for (int dt = 0; dt < 2; ++dt)
          #pragma unroll
          for (int r = 0; r < 4; ++r) ss += sk[dt][nt][r] * sk[dt][nt][r];
        ss += __shfl_xor(ss, 16);
        ss += __shfl_xor(ss, 32);
        float rn = 1.0f / fmaxf(sqrtf(ss), 1e-12f);
        kA[nt] = xposeS(pk2(sk[0][nt][0] * rn, sk[0][nt][1] * rn), pk2(sk[0][nt][2] * rn, sk[0][nt][3] * rn),
                        pk2(sk[1][nt][0] * rn, sk[1][nt][1] * rn), pk2(sk[1][nt][2] * rn, sk[1][nt][3] * rn), lane);
      }
    }
    // ---- v: +bias, pack -> v^T A-frags vA[dt][kt] ----
    {
      const float vb0 = qkvb[512 + h * 32 + lq];
      const float vb1 = qkvb[512 + h * 32 + 16 + lq];
      unsigned vp[4][2][2];
      #pragma unroll
      for (int mt = 0; mt < 4; ++mt) {
        vp[mt][0][0] = pk2(sv[mt][0][0] + vb0, sv[mt][0][1] + vb0);
        vp[mt][0][1] = pk2(sv[mt][0][2] + vb0, sv[mt][0][3] + vb0);
        vp[mt][1][0] = pk2(sv[mt][1][0] + vb1, sv[mt][1][1] + vb1);
        vp[mt][1][1] = pk2(sv[mt][1][2] + vb1, sv[mt][1][3] + vb1);
      }
      #pragma unroll
      for (int dt = 0; dt < 2; ++dt)
        #pragma unroll
        for (int kt = 0; kt < 2; ++kt)
          vA[dt][kt] = xposeS(vp[2 * kt][dt][0], vp[2 * kt][dt][1],
                              vp[2 * kt + 1][dt][0], vp[2 * kt + 1][dt][1], lane);
    }

    // ---- S^T[key][query] = mfma(kA, qB) ----
    f32x4 sT[4][4];
    #pragma unroll
    for (int nt = 0; nt < 4; ++nt)
      #pragma unroll
      for (int mt = 0; mt < 4; ++mt)
        sT[nt][mt] = __builtin_amdgcn_mfma_f32_16x16x32_bf16(kA[nt], qB[mt], fz, 0, 0, 0);

    // ---- softmax over keys (16 in-lane + shfl 16/32), pack P^T pairs ----
    const float sch = scale[h];
    unsigned pp[4][4][2];   // [mt][nt][c]
    #pragma unroll
    for (int mt = 0; mt < 4; ++mt) {
      f32x4 rp[4];
      #pragma unroll
      for (int nt = 0; nt < 4; ++nt)
        rp[nt] = ((const f32x4*)rpb)[((h * 4 + mt) * 4 + nt) * 64 + lane];
      float ee[4][4];
      float mx = -3.0e38f;
      #pragma unroll
      for (int nt = 0; nt < 4; ++nt)
        #pragma unroll
        for (int r = 0; r < 4; ++r) {
          float vv = sT[nt][mt][r] * sch + rp[nt][r];
          ee[nt][r] = vv;
          mx = fmaxf(mx, vv);
        }
      mx = fmaxf(mx, __shfl_xor(mx, 16));
      mx = fmaxf(mx, __shfl_xor(mx, 32));
      float sm = 0.0f;
      #pragma unroll
      for (int nt = 0; nt < 4; ++nt)
        #pragma unroll
        for (int r = 0; r < 4; ++r) {
          ee[nt][r] = __expf(ee[nt][r] - mx);
          sm += ee[nt][r];
        }
      sm += __shfl_xor(sm, 16);
      sm += __shfl_xor(sm, 32);
      float inv = 1.0f / sm;
      #pragma unroll
      for (int nt = 0; nt < 4; ++nt) {
        pp[mt][nt][0] = pk2(ee[nt][0] * inv, ee[nt][1] * inv);
        pp[mt][nt][1] = pk2(ee[nt][2] * inv, ee[nt][3] * inv);
      }
    }

    // ---- PV: out^T = v^T · P^T -> otk[hi] (held in regs) ----
    #pragma unroll
    for (int dt = 0; dt < 2; ++dt)
      #pragma unroll
      for (int mt = 0; mt < 4; ++mt) otk[hi][dt][mt] = fz;
    #pragma unroll
    for (int kt = 0; kt < 2; ++kt) {
      bf16x8 pB[4];
      #pragma unroll
      for (int mt = 0; mt < 4; ++mt)
        pB[mt] = xposeS(pp[mt][2 * kt][0], pp[mt][2 * kt][1],
                        pp[mt][2 * kt + 1][0], pp[mt][2 * kt + 1][1], lane);
      #pragma unroll
      for (int dt = 0; dt < 2; ++dt)
        #pragma unroll
        for (int mt = 0; mt < 4; ++mt)
          otk[hi][dt][mt] = __builtin_amdgcn_mfma_f32_16x16x32_bf16(vA[dt][kt], pB[mt], otk[hi][dt][mt], 0, 0, 0);
    }
  }  // hi

  // ---- all xb reads done: overlay ob on sbuf (f2bf pack — acc-safe) ----
  __syncthreads();
  #pragma unroll
  for (int hi = 0; hi < 2; ++hi) {
    const int h = wid + hi * 4;
    #pragma unroll
    for (int dt = 0; dt < 2; ++dt)
      #pragma unroll
      for (int mt = 0; mt < 4; ++mt) {
        short4v pk;
        #pragma unroll
        for (int r = 0; r < 4; ++r) pk[r] = (short)f2bf(otk[hi][dt][mt][r]);
        *(short4v*)&sbuf[(mt * 16 + lq) * 264 + h * 32 + dt * 16 + lg * 4] = pk;
      }
  }
  __syncthreads();

  // ---- proj: out = ob · Wp^T + b (wave w -> cols [w*64, w*64+64)) ----
  {
    f32x4 acc[4][4];
    #pragma unroll
    for (int mt = 0; mt < 4; ++mt)
      #pragma unroll
      for (int nt = 0; nt < 4; ++nt) acc[mt][nt] = fz;
    const int c0 = wid * 64;
    #pragma unroll 2
    for (int ks = 0; ks < 8; ++ks) {
      const int k0 = ks * 32;
      bf16x8 a[4], b[4];
      #pragma unroll
      for (int mt = 0; mt < 4; ++mt)
        a[mt] = *(const bf16x8*)&sbuf[(mt * 16 + lq) * 264 + k0 + lg * 8];
      #pragma unroll
      for (int nt = 0; nt < 4; ++nt)
        b[nt] = *(const bf16x8*)&wproj[(c0 + nt * 16 + lq) * 256 + k0 + lg * 8];
      #pragma unroll
      for (int mt = 0; mt < 4; ++mt)
        #pragma unroll
        for (int nt = 0; nt < 4; ++nt)
          acc[mt][nt] = __builtin_amdgcn_mfma_f32_16x16x32_bf16(a[mt], b[nt], acc[mt][nt], 0, 0, 0);
    }
    #pragma unroll
    for (int nt = 0; nt < 4; ++nt) {
      const float pbv = projb[c0 + nt * 16 + lq];
      #pragma unroll
      for (int mt = 0; mt < 4; ++mt)
        #pragma unroll
        for (int r = 0; r < 4; ++r) {
          const int row = mt * 16 + lg * 4 + r;
          out[((size_t)blk * 64 + row) * 256 + c0 + nt * 16 + lq] = acc[mt][nt][r] + pbv;
        }
    }
  }
}

extern "C" void kernel_launch(void* const* d_in, const int* in_sizes, int n_in,
                              void* d_out, int out_size, void* d_ws, size_t ws_size,
                              hipStream_t stream) {
  const float* x     = (const float*)d_in[0];
  const float* qkvw  = (const float*)d_in[1];
  const float* qbias = (const float*)d_in[2];
  const float* vbias = (const float*)d_in[3];
  const float* ls    = (const float*)d_in[4];
  const float* w1    = (const float*)d_in[5];
  const float* b1    = (const float*)d_in[6];
  const float* w2    = (const float*)d_in[7];
  const float* pw    = (const float*)d_in[8];
  const float* pbias = (const float*)d_in[9];
  float* out = (float*)d_out;

  char* ws = (char*)d_ws;
  short* wqkv_bf  = (short*)(ws);                 // 393216 B
  short* wproj_bf = (short*)(ws + 393216);        // 131072 B
  float* rpb      = (float*)(ws + 524288);        // 131072 B
  float* scale    = (float*)(ws + 655360);        // 32 B
  float* qkvb     = (float*)(ws + 655392);        // 3072 B
  float* bt       = (float*)(ws + 658464);        // 4064 B

  cpb_table_kernel<<<dim3(127), dim3(64), 0, stream>>>(w1, b1, w2, bt);
  cpb_expand_kernel<<<dim3(128), dim3(256), 0, stream>>>(bt, ls, rpb, scale);
  convert_kernel<<<dim3(1024), dim3(256), 0, stream>>>(qkvw, pw, qbias, vbias,
                                                       wqkv_bf, wproj_bf, qkvb);
  win_attn_kernel<<<dim3(2048), dim3(256), 0, stream>>>(x, wqkv_bf, wproj_bf, qkvb,
                                                        scale, rpb, pbias, out);
}